// Round 8
// baseline (154.350 us; speedup 1.0000x reference)
//
#include <hip/hip_runtime.h>

// Problem constants
#define NTOK   2048
#define DIM    64
#define NCODES 50000
#define THRESH 100.0f
#define BIG    3.0e38f
#define MARGIN 4.0f      // rigorous 2E bound ~2.5; safety margin
#define NBLK   391       // 128-code MFMA blocks
#define NCG    128       // code groups: first 7 have 4 blocks, rest 3 (7*4+121*3=391)
#define BMP    416       // bmT row stride in floats (416*4 = 1664 B = 13 lines)

typedef __attribute__((ext_vector_type(8)))  __bf16 bf16x8;
typedef __attribute__((ext_vector_type(16))) float  float16;

__device__ __forceinline__ unsigned short f2bf(float f) {
    union { float f; unsigned int u; } v; v.f = f;
    unsigned int r = v.u + 0x7FFF + ((v.u >> 16) & 1);
    return (unsigned short)(r >> 16);
}
__device__ __forceinline__ unsigned int pack2(float a, float b) {
    return (unsigned int)f2bf(a) | ((unsigned int)f2bf(b) << 16);
}
// log-depth max of 16 (pairwise tree; clang fuses into v_max3 chains)
__device__ __forceinline__ float max16(const float16& v) {
    float a = fmaxf(v[0], v[1]),   b = fmaxf(v[2], v[3]);
    float c = fmaxf(v[4], v[5]),   d = fmaxf(v[6], v[7]);
    float e = fmaxf(v[8], v[9]),   f = fmaxf(v[10], v[11]);
    float g = fmaxf(v[12], v[13]), h = fmaxf(v[14], v[15]);
    a = fmaxf(a, b); c = fmaxf(c, d); e = fmaxf(e, f); g = fmaxf(g, h);
    return fmaxf(fmaxf(a, c), fmaxf(e, g));
}

// ---------------------------------------------------------------------------
// Kernel 1 (prep): fp32 -> bf16 of codes and x, code norms. 4 lanes per row
// (64 B per lane), 2-step shfl for the norm. Verified body (rounds 0, 6).
// ---------------------------------------------------------------------------
__global__ __launch_bounds__(256)
void nn_prep_kernel(const float* __restrict__ x, const float* __restrict__ codes,
                    unsigned short* __restrict__ cbf, unsigned short* __restrict__ xbf,
                    float* __restrict__ c2) {
    int g = blockIdx.x * 256 + threadIdx.x;
    int row = g >> 2;
    int seg = g & 3;
    const float* src;
    unsigned short* dst;
    float* nrm;
    if (row < NCODES) {
        src = codes + (size_t)row * DIM + seg * 16;
        dst = cbf + (size_t)row * DIM + seg * 16;
        nrm = (seg == 0) ? (c2 + row) : nullptr;
    } else if (row < NCODES + NTOK) {
        int r = row - NCODES;
        src = x + (size_t)r * DIM + seg * 16;
        dst = xbf + (size_t)r * DIM + seg * 16;
        nrm = nullptr;
    } else {
        return;
    }
    float4 v0 = ((const float4*)src)[0];
    float4 v1 = ((const float4*)src)[1];
    float4 v2 = ((const float4*)src)[2];
    float4 v3 = ((const float4*)src)[3];
    float s = 0.f;
    s = fmaf(v0.x, v0.x, s); s = fmaf(v0.y, v0.y, s);
    s = fmaf(v0.z, v0.z, s); s = fmaf(v0.w, v0.w, s);
    s = fmaf(v1.x, v1.x, s); s = fmaf(v1.y, v1.y, s);
    s = fmaf(v1.z, v1.z, s); s = fmaf(v1.w, v1.w, s);
    s = fmaf(v2.x, v2.x, s); s = fmaf(v2.y, v2.y, s);
    s = fmaf(v2.z, v2.z, s); s = fmaf(v2.w, v2.w, s);
    s = fmaf(v3.x, v3.x, s); s = fmaf(v3.y, v3.y, s);
    s = fmaf(v3.z, v3.z, s); s = fmaf(v3.w, v3.w, s);
    uint4 lo, hi;
    lo.x = pack2(v0.x, v0.y); lo.y = pack2(v0.z, v0.w);
    lo.z = pack2(v1.x, v1.y); lo.w = pack2(v1.z, v1.w);
    hi.x = pack2(v2.x, v2.y); hi.y = pack2(v2.z, v2.w);
    hi.z = pack2(v3.x, v3.y); hi.w = pack2(v3.z, v3.w);
    *(uint4*)dst = lo;
    *(uint4*)(dst + 8) = hi;
    s += __shfl_xor(s, 1);
    s += __shfl_xor(s, 2);
    if (nrm) *nrm = s;
}

// ---------------------------------------------------------------------------
// Kernel 2 (stage A): bf16 MFMA screening from prep's bf16 buffers.
// Output: bmT[token][blk] TOKEN-MAJOR (row stride BMP=416 floats = 13 lines)
// so finalize scans its row with coalesced contiguous loads (round 6's
// blk-major layout forced a stride-8KB scan: 82 MB line traffic, 71 us).
// Writer-side scatter is absorbed in L2 by the grid decode below:
// 1-D grid 1024, gi = (bid&7)*16 + (bid>>6), sy = (bid>>3)&7. XCD (= bid%8)
// hosts a CONTIGUOUS 16-gi cluster x all 8 supertiles. A bmT line (32
// consecutive blks of one token) is written by ~10 consecutive gi's ->
// almost always one XCD -> dirty lines merge in that XCD's L2, one
// writeback (~4 MB). Codes per XCD = 16 gi ~0.8 MB bf16, L2-resident,
// shared by the 8 supertile copies. Both reader and writer coalesced.
// (256,2): proven 120-VGPR/no-spill config (round 3's (256,4) spilled).
// ---------------------------------------------------------------------------
__global__ __launch_bounds__(256, 2)
void nn_stageA_kernel(const unsigned short* __restrict__ xbf,
                      const unsigned short* __restrict__ cbf,
                      const float* __restrict__ c2g,
                      float* __restrict__ bmT) {
    __shared__ __bf16 cs[128 * 72];   // code tile, 144 B row stride
    __shared__ float  c2s[128];       // holds -c2/2 per tile row

    const int tid  = threadIdx.x;
    const int w    = tid >> 6;
    const int lane = tid & 63;
    const int l31  = lane & 31;
    const int h    = lane >> 5;
    const int bid  = blockIdx.x;
    const int gi   = (bid & 7) * 16 + (bid >> 6);   // [0,128) code group
    const int sy   = (bid >> 3) & 7;                // [0,8) token supertile
    const int g0   = 3 * gi + min(gi, 7);
    const int nb   = (gi < 7) ? 4 : 3;
    const int t0   = sy * 256;

    // B fragments (tokens w*64..w*64+63), loop-invariant, bf16 direct loads
    bf16x8 bfr[4][2];
#pragma unroll
    for (int s = 0; s < 4; ++s)
#pragma unroll
        for (int nj = 0; nj < 2; ++nj)
            bfr[s][nj] = *(const bf16x8*)&xbf[
                (size_t)(t0 + w * 64 + nj * 32 + l31) * DIM + s * 16 + h * 8];

    // code-tile register prefetch: 128 rows x 128 B bf16; 8 lanes/row, 16 B/lane
    uint4 pr[4];
    float prc;
    auto prefetch = [&](int blk) {
        int n0 = blk * 128;
#pragma unroll
        for (int it = 0; it < 4; ++it) {
            int g = it * 256 + tid;
            int row = g >> 3, seg = g & 7;
            int n = n0 + row;
            pr[it] = (n < NCODES) ? *(const uint4*)(cbf + (size_t)n * DIM + seg * 8)
                                  : make_uint4(0, 0, 0, 0);
        }
        if (tid < 128) {
            int n = n0 + tid;
            prc = (n < NCODES) ? c2g[n] : BIG;
        }
    };
    prefetch(g0);

    for (int t = 0; t < nb; ++t) {
        const int blk = g0 + t;
        __syncthreads();   // previous iter's readers done with cs/c2s

        // regs -> LDS (conflict-free); c2s gets -c2/2 directly
#pragma unroll
        for (int it = 0; it < 4; ++it) {
            int g = it * 256 + tid;
            int row = g >> 3, seg = g & 7;
            *(uint4*)&cs[row * 72 + seg * 8] = pr[it];
        }
        if (tid < 128) c2s[tid] = -0.5f * prc;
        if (t + 1 < nb) prefetch(blk + 1);   // latency hides under compute
        __syncthreads();

        // acc[mi][nj][r] = -c2[code_row]/2  (c2s reads are 2-addr broadcasts)
        // C/D: col = lane&31 (token), row = (r&3) + 8*(r>>2) + 4*h (code)
        float16 acc[4][2];
#pragma unroll
        for (int mi = 0; mi < 4; ++mi)
#pragma unroll
            for (int g2 = 0; g2 < 4; ++g2) {
                float4 c4 = *(float4*)&c2s[mi * 32 + g2 * 8 + 4 * h];
#pragma unroll
                for (int i = 0; i < 4; ++i) {
                    float iv = ((float*)&c4)[i];
                    acc[mi][0][g2 * 4 + i] = iv;
                    acc[mi][1][g2 * 4 + i] = iv;
                }
            }

        // K = 64 in 4 steps of 16; A from LDS, B from registers
#pragma unroll
        for (int s = 0; s < 4; ++s) {
            bf16x8 a[4];
#pragma unroll
            for (int mi = 0; mi < 4; ++mi)
                a[mi] = *(bf16x8*)&cs[(mi * 32 + l31) * 72 + s * 16 + h * 8];
#pragma unroll
            for (int mi = 0; mi < 4; ++mi)
#pragma unroll
                for (int nj = 0; nj < 2; ++nj)
                    acc[mi][nj] = __builtin_amdgcn_mfma_f32_32x32x16_bf16(
                        a[mi], bfr[s][nj], acc[mi][nj], 0, 0, 0);
        }

        // epilogue: ONE screen value per token for this 128-code blk
        // = -2 * max over all mi/r/h. lanes<32 carry nj=0 (tokens +0..31),
        // lanes>=32 carry nj=1 (tokens +32..63). Per-lane dword scatter to
        // token rows — merges in the XCD-local L2 (grid decode above).
        // (invalid rows carry ~-1.5e38 from -BIG/2 init -> never win the max)
        float sv[2];
#pragma unroll
        for (int nj = 0; nj < 2; ++nj) {
            float m = max16(acc[0][nj]);
            m = fmaxf(m, max16(acc[1][nj]));
            m = fmaxf(m, max16(acc[2][nj]));
            m = fmaxf(m, max16(acc[3][nj]));
            m = fmaxf(m, __shfl_xor(m, 32));  // merge h halves
            sv[nj] = -2.0f * m;
        }
        bmT[(size_t)(t0 + w * 64 + lane) * BMP + blk] = (lane < 32) ? sv[0] : sv[1];
    }
}

// ---------------------------------------------------------------------------
// Kernel 3 (finalize): one WG per token (2048 WGs). Scan = the token's OWN
// contiguous bmT row (391 floats, 13 lines, 2 coalesced loads/thread; round 6
// scanned at stride 8 KB -> 82 MB of line traffic). Reduce -> threshold ->
// blk-granularity queue -> whole-WG exact-fp32 rescore (wave w takes codes
// blk*128 + w*32 + (lane>>1)); inner math verbatim from rounds 1-6 passing
// kernels (fmaf order, pair shfl, on-the-fly x2/c2).
// ---------------------------------------------------------------------------
__global__ __launch_bounds__(256)
void nn_finalize_kernel(const float* __restrict__ x,
                        const float* __restrict__ codes,
                        const float* __restrict__ bmT,
                        int* __restrict__ out) {
    __shared__ float redf[8];      // [0..3] wave gmin, [4..7] wave best-v
    __shared__ int   redi[4];
    __shared__ int   queue[NBLK];
    __shared__ int   qcount;
    __shared__ float gshare;

    const int tid  = threadIdx.x;
    const int w    = tid >> 6;
    const int lane = tid & 63;
    const int t    = blockIdx.x;
    const float* bp = bmT + (size_t)t * BMP;

    if (tid == 0) qcount = 0;

    float v0 = (tid < NBLK) ? bp[tid] : BIG;
    float v1 = (tid + 256 < NBLK) ? bp[tid + 256] : BIG;

    float g = fminf(v0, v1);
#pragma unroll
    for (int m = 1; m < 64; m <<= 1) g = fminf(g, __shfl_xor(g, m));
    if (lane == 0) redf[w] = g;
    __syncthreads();
    if (tid == 0)
        gshare = fminf(fminf(redf[0], redf[1]), fminf(redf[2], redf[3])) + MARGIN;
    __syncthreads();
    const float th = gshare;

    // enqueue candidate 128-code blocks (order irrelevant — (v,id) total order)
    if (v0 <= th) queue[atomicAdd(&qcount, 1)] = tid;
    if (tid + 256 < NBLK && v1 <= th) queue[atomicAdd(&qcount, 1)] = tid + 256;
    __syncthreads();
    const int nq = qcount;

    // per-lane x half-row (half = lane&1 -> dims [0,32) or [32,64))
    const int half = lane & 1;
    float4 xh[8];
#pragma unroll
    for (int q = 0; q < 8; ++q)
        xh[q] = *(const float4*)(x + (size_t)t * DIM + half * 32 + q * 4);
    float x2v = 0.f;
#pragma unroll
    for (int q = 0; q < 8; ++q) {
        x2v = fmaf(xh[q].x, xh[q].x, x2v);
        x2v = fmaf(xh[q].y, xh[q].y, x2v);
        x2v = fmaf(xh[q].z, xh[q].z, x2v);
        x2v = fmaf(xh[q].w, xh[q].w, x2v);
    }
    x2v += __shfl_xor(x2v, 1);   // full ||x||^2 in both pair lanes

    float bv = BIG;
    int   bi = 0x7fffffff;
    for (int e = 0; e < nq; ++e) {
        int blk = queue[e];
        int n = blk * 128 + w * 32 + (lane >> 1);   // whole WG per candidate
        if (n < NCODES) {   // pair-uniform predicate
            const float4* cp = (const float4*)(codes + (size_t)n * DIM + half * 32);
            float d = 0.f, cq = 0.f;
#pragma unroll
            for (int q = 0; q < 8; ++q) {
                float4 c4 = cp[q];
                d  = fmaf(xh[q].x, c4.x, d);
                d  = fmaf(xh[q].y, c4.y, d);
                d  = fmaf(xh[q].z, c4.z, d);
                d  = fmaf(xh[q].w, c4.w, d);
                cq = fmaf(c4.x, c4.x, cq);
                cq = fmaf(c4.y, c4.y, cq);
                cq = fmaf(c4.z, c4.z, cq);
                cq = fmaf(c4.w, c4.w, cq);
            }
            d  += __shfl_xor(d, 1);    // full 64-dim dot in both pair lanes
            cq += __shfl_xor(cq, 1);   // full ||c||^2 in both pair lanes
            float d2 = fmaxf(fmaf(-2.f, d, x2v + cq), 0.f);
            if (d2 < bv || (d2 == bv && n < bi)) { bv = d2; bi = n; }
        }
    }
#pragma unroll
    for (int m = 1; m < 64; m <<= 1) {
        float vv = __shfl_xor(bv, m);
        int   ii = __shfl_xor(bi, m);
        if (vv < bv || (vv == bv && ii < bi)) { bv = vv; bi = ii; }
    }
    if (lane == 0) { redf[4 + w] = bv; redi[w] = bi; }
    __syncthreads();
    if (tid == 0) {
        float fb = BIG;
        int   fi = 0x7fffffff;
#pragma unroll
        for (int i = 0; i < 4; ++i) {
            float vv = redf[4 + i];
            int   ii = redi[i];
            if (vv < fb || (vv == fb && ii < fi)) { fb = vv; fi = ii; }
        }
        out[t] = (fb <= THRESH) ? fi : -1;
    }
}

// ---------------------------------------------------------------------------
// Workspace: c2[50048]f | cbf[50000*64]u16 | xbf[2048*64]u16 |
//            bmT[2048*416]f  (~10.5 MB total; all offsets 16 B-aligned)
// ---------------------------------------------------------------------------
extern "C" void kernel_launch(void* const* d_in, const int* in_sizes, int n_in,
                              void* d_out, int out_size, void* d_ws, size_t ws_size,
                              hipStream_t stream) {
    const float* x     = (const float*)d_in[0];  // [2,1024,64]
    const float* codes = (const float*)d_in[1];  // [50000,64]

    float* c2 = (float*)d_ws;
    unsigned short* cbf = (unsigned short*)(c2 + 50048);
    unsigned short* xbf = cbf + (size_t)NCODES * DIM;
    float* bmT = (float*)(xbf + (size_t)NTOK * DIM);
    int* out = (int*)d_out;

    nn_prep_kernel<<<814, 256, 0, stream>>>(x, codes, cbf, xbf, c2);
    nn_stageA_kernel<<<1024, 256, 0, stream>>>(xbf, cbf, c2, bmT);
    nn_finalize_kernel<<<NTOK, 256, 0, stream>>>(x, codes, bmT, out);
}

// Round 9
// 115.228 us; speedup vs baseline: 1.3395x; 1.3395x over previous
//
#include <hip/hip_runtime.h>

// Problem constants
#define NTOK   2048
#define DIM    64
#define NCODES 50000
#define THRESH 100.0f
#define BIG    3.0e38f
#define MARGIN 1.0f      // fp16 screen: E<=~0.22 rigorous, 2E<=0.45; 2x safety
#define NBLK   391       // 128-code MFMA blocks
#define NCG    128       // code groups: first 7 have 4 blocks, rest 3 (7*4+121*3=391)
#define BMP    416       // bmT row stride in floats (416*4 = 1664 B = 13 lines)

typedef __attribute__((ext_vector_type(8)))  _Float16 f16x8;
typedef __attribute__((ext_vector_type(16))) float    float16;

__device__ __forceinline__ unsigned short f2h(float f) {
    union { _Float16 h; unsigned short u; } v;
    v.h = (_Float16)f;           // v_cvt_f16_f32, round-to-nearest-even
    return v.u;
}
__device__ __forceinline__ unsigned int pack2h(float a, float b) {
    return (unsigned int)f2h(a) | ((unsigned int)f2h(b) << 16);
}
// log-depth max of 16 (pairwise tree; clang fuses into v_max3 chains)
__device__ __forceinline__ float max16(const float16& v) {
    float a = fmaxf(v[0], v[1]),   b = fmaxf(v[2], v[3]);
    float c = fmaxf(v[4], v[5]),   d = fmaxf(v[6], v[7]);
    float e = fmaxf(v[8], v[9]),   f = fmaxf(v[10], v[11]);
    float g = fmaxf(v[12], v[13]), h = fmaxf(v[14], v[15]);
    a = fmaxf(a, b); c = fmaxf(c, d); e = fmaxf(e, f); g = fmaxf(g, h);
    return fmaxf(fmaxf(a, c), fmaxf(e, g));
}

// ---------------------------------------------------------------------------
// Kernel 1 (prep): fp32 -> fp16 of codes and x, code norms (exact fp32).
// 4 lanes per row (64 B per lane), 2-step shfl for the norm. Same structure
// as the verified bf16 prep (rounds 0/6/8); only the pack target changed.
// fp16 instead of bf16 cuts the screen error E from ~2.5 to ~0.22, which
// lets MARGIN drop 4.0 -> 1.0 and shrinks the finalize candidate set ~8x
// (round 8: FETCH 80 MB of L2-thrashed candidate gathers = 73 us).
// ---------------------------------------------------------------------------
__global__ __launch_bounds__(256)
void nn_prep_kernel(const float* __restrict__ x, const float* __restrict__ codes,
                    unsigned short* __restrict__ ch, unsigned short* __restrict__ xh,
                    float* __restrict__ c2) {
    int g = blockIdx.x * 256 + threadIdx.x;
    int row = g >> 2;
    int seg = g & 3;
    const float* src;
    unsigned short* dst;
    float* nrm;
    if (row < NCODES) {
        src = codes + (size_t)row * DIM + seg * 16;
        dst = ch + (size_t)row * DIM + seg * 16;
        nrm = (seg == 0) ? (c2 + row) : nullptr;
    } else if (row < NCODES + NTOK) {
        int r = row - NCODES;
        src = x + (size_t)r * DIM + seg * 16;
        dst = xh + (size_t)r * DIM + seg * 16;
        nrm = nullptr;
    } else {
        return;
    }
    float4 v0 = ((const float4*)src)[0];
    float4 v1 = ((const float4*)src)[1];
    float4 v2 = ((const float4*)src)[2];
    float4 v3 = ((const float4*)src)[3];
    float s = 0.f;
    s = fmaf(v0.x, v0.x, s); s = fmaf(v0.y, v0.y, s);
    s = fmaf(v0.z, v0.z, s); s = fmaf(v0.w, v0.w, s);
    s = fmaf(v1.x, v1.x, s); s = fmaf(v1.y, v1.y, s);
    s = fmaf(v1.z, v1.z, s); s = fmaf(v1.w, v1.w, s);
    s = fmaf(v2.x, v2.x, s); s = fmaf(v2.y, v2.y, s);
    s = fmaf(v2.z, v2.z, s); s = fmaf(v2.w, v2.w, s);
    s = fmaf(v3.x, v3.x, s); s = fmaf(v3.y, v3.y, s);
    s = fmaf(v3.z, v3.z, s); s = fmaf(v3.w, v3.w, s);
    uint4 lo, hi;
    lo.x = pack2h(v0.x, v0.y); lo.y = pack2h(v0.z, v0.w);
    lo.z = pack2h(v1.x, v1.y); lo.w = pack2h(v1.z, v1.w);
    hi.x = pack2h(v2.x, v2.y); hi.y = pack2h(v2.z, v2.w);
    hi.z = pack2h(v3.x, v3.y); hi.w = pack2h(v3.z, v3.w);
    *(uint4*)dst = lo;
    *(uint4*)(dst + 8) = hi;
    s += __shfl_xor(s, 1);
    s += __shfl_xor(s, 2);
    if (nrm) *nrm = s;
}

// ---------------------------------------------------------------------------
// Kernel 2 (stage A): fp16 MFMA screening (mfma_f32_32x32x16_f16 — same rate
// as bf16, measured 2178 vs 2382 TF). Structure identical to the verified
// round-8 kernel; only dtype + intrinsic changed.
// Output: bmT[token][blk] TOKEN-MAJOR (row stride BMP=416 floats = 13 lines).
// Grid decode: gi = (bid&7)*16 + (bid>>6), sy = (bid>>3)&7 -> XCD (= bid%8)
// hosts a CONTIGUOUS 16-gi cluster x all 8 supertiles (writer lines merge in
// XCD-local L2; codes slice ~0.8 MB f16, L2-resident).
// (256,2): proven 120-VGPR/no-spill config (round 3's (256,4) spilled).
// ---------------------------------------------------------------------------
__global__ __launch_bounds__(256, 2)
void nn_stageA_kernel(const unsigned short* __restrict__ xh,
                      const unsigned short* __restrict__ ch,
                      const float* __restrict__ c2g,
                      float* __restrict__ bmT) {
    __shared__ _Float16 cs[128 * 72];   // code tile, 144 B row stride
    __shared__ float    c2s[128];       // holds -c2/2 per tile row

    const int tid  = threadIdx.x;
    const int w    = tid >> 6;
    const int lane = tid & 63;
    const int l31  = lane & 31;
    const int h    = lane >> 5;
    const int bid  = blockIdx.x;
    const int gi   = (bid & 7) * 16 + (bid >> 6);   // [0,128) code group
    const int sy   = (bid >> 3) & 7;                // [0,8) token supertile
    const int g0   = 3 * gi + min(gi, 7);
    const int nb   = (gi < 7) ? 4 : 3;
    const int t0   = sy * 256;

    // B fragments (tokens w*64..w*64+63), loop-invariant, f16 direct loads
    f16x8 bfr[4][2];
#pragma unroll
    for (int s = 0; s < 4; ++s)
#pragma unroll
        for (int nj = 0; nj < 2; ++nj)
            bfr[s][nj] = *(const f16x8*)&xh[
                (size_t)(t0 + w * 64 + nj * 32 + l31) * DIM + s * 16 + h * 8];

    // code-tile register prefetch: 128 rows x 128 B f16; 8 lanes/row, 16 B/lane
    uint4 pr[4];
    float prc;
    auto prefetch = [&](int blk) {
        int n0 = blk * 128;
#pragma unroll
        for (int it = 0; it < 4; ++it) {
            int g = it * 256 + tid;
            int row = g >> 3, seg = g & 7;
            int n = n0 + row;
            pr[it] = (n < NCODES) ? *(const uint4*)(ch + (size_t)n * DIM + seg * 8)
                                  : make_uint4(0, 0, 0, 0);
        }
        if (tid < 128) {
            int n = n0 + tid;
            prc = (n < NCODES) ? c2g[n] : BIG;
        }
    };
    prefetch(g0);

    for (int t = 0; t < nb; ++t) {
        const int blk = g0 + t;
        __syncthreads();   // previous iter's readers done with cs/c2s

        // regs -> LDS (conflict-free); c2s gets -c2/2 directly
#pragma unroll
        for (int it = 0; it < 4; ++it) {
            int g = it * 256 + tid;
            int row = g >> 3, seg = g & 7;
            *(uint4*)&cs[row * 72 + seg * 8] = pr[it];
        }
        if (tid < 128) c2s[tid] = -0.5f * prc;
        if (t + 1 < nb) prefetch(blk + 1);   // latency hides under compute
        __syncthreads();

        // acc[mi][nj][r] = -c2[code_row]/2  (c2s reads are 2-addr broadcasts)
        // C/D: col = lane&31 (token), row = (r&3) + 8*(r>>2) + 4*h (code)
        float16 acc[4][2];
#pragma unroll
        for (int mi = 0; mi < 4; ++mi)
#pragma unroll
            for (int g2 = 0; g2 < 4; ++g2) {
                float4 c4 = *(float4*)&c2s[mi * 32 + g2 * 8 + 4 * h];
#pragma unroll
                for (int i = 0; i < 4; ++i) {
                    float iv = ((float*)&c4)[i];
                    acc[mi][0][g2 * 4 + i] = iv;
                    acc[mi][1][g2 * 4 + i] = iv;
                }
            }

        // K = 64 in 4 steps of 16; A from LDS, B from registers
#pragma unroll
        for (int s = 0; s < 4; ++s) {
            f16x8 a[4];
#pragma unroll
            for (int mi = 0; mi < 4; ++mi)
                a[mi] = *(f16x8*)&cs[(mi * 32 + l31) * 72 + s * 16 + h * 8];
#pragma unroll
            for (int mi = 0; mi < 4; ++mi)
#pragma unroll
                for (int nj = 0; nj < 2; ++nj)
                    acc[mi][nj] = __builtin_amdgcn_mfma_f32_32x32x16_f16(
                        a[mi], bfr[s][nj], acc[mi][nj], 0, 0, 0);
        }

        // epilogue: ONE screen value per token for this 128-code blk
        // = -2 * max over all mi/r/h. lanes<32 carry nj=0 (tokens +0..31),
        // lanes>=32 carry nj=1 (tokens +32..63). Per-lane dword scatter to
        // token rows — merges in the XCD-local L2 (grid decode above).
        // (invalid rows carry ~-1.5e38 from -BIG/2 init -> never win the max)
        float sv[2];
#pragma unroll
        for (int nj = 0; nj < 2; ++nj) {
            float m = max16(acc[0][nj]);
            m = fmaxf(m, max16(acc[1][nj]));
            m = fmaxf(m, max16(acc[2][nj]));
            m = fmaxf(m, max16(acc[3][nj]));
            m = fmaxf(m, __shfl_xor(m, 32));  // merge h halves
            sv[nj] = -2.0f * m;
        }
        bmT[(size_t)(t0 + w * 64 + lane) * BMP + blk] = (lane < 32) ? sv[0] : sv[1];
    }
}

// ---------------------------------------------------------------------------
// Kernel 3 (finalize): one WG per token (2048 WGs). Scan = the token's OWN
// contiguous bmT row (391 floats, 13 lines, 2 coalesced loads/thread).
// Reduce -> threshold (gmin + 1.0, fp16-tight) -> blk-granularity queue ->
// whole-WG exact-fp32 rescore (wave w takes codes blk*128 + w*32 + (lane>>1));
// inner math verbatim from rounds 1-8 passing kernels (fmaf order, pair shfl,
// on-the-fly x2/c2). Margin argument: screen(B(n*)) <= s(n*)+E and
// gmin >= s(n*)-E, so MARGIN >= 2E (~0.45) suffices; 1.0 gives 2x safety.
// ---------------------------------------------------------------------------
__global__ __launch_bounds__(256)
void nn_finalize_kernel(const float* __restrict__ x,
                        const float* __restrict__ codes,
                        const float* __restrict__ bmT,
                        int* __restrict__ out) {
    __shared__ float redf[8];      // [0..3] wave gmin, [4..7] wave best-v
    __shared__ int   redi[4];
    __shared__ int   queue[NBLK];
    __shared__ int   qcount;
    __shared__ float gshare;

    const int tid  = threadIdx.x;
    const int w    = tid >> 6;
    const int lane = tid & 63;
    const int t    = blockIdx.x;
    const float* bp = bmT + (size_t)t * BMP;

    if (tid == 0) qcount = 0;

    float v0 = (tid < NBLK) ? bp[tid] : BIG;
    float v1 = (tid + 256 < NBLK) ? bp[tid + 256] : BIG;

    float g = fminf(v0, v1);
#pragma unroll
    for (int m = 1; m < 64; m <<= 1) g = fminf(g, __shfl_xor(g, m));
    if (lane == 0) redf[w] = g;
    __syncthreads();
    if (tid == 0)
        gshare = fminf(fminf(redf[0], redf[1]), fminf(redf[2], redf[3])) + MARGIN;
    __syncthreads();
    const float th = gshare;

    // enqueue candidate 128-code blocks (order irrelevant — (v,id) total order)
    if (v0 <= th) queue[atomicAdd(&qcount, 1)] = tid;
    if (tid + 256 < NBLK && v1 <= th) queue[atomicAdd(&qcount, 1)] = tid + 256;
    __syncthreads();
    const int nq = qcount;

    // per-lane x half-row (half = lane&1 -> dims [0,32) or [32,64))
    const int half = lane & 1;
    float4 xh[8];
#pragma unroll
    for (int q = 0; q < 8; ++q)
        xh[q] = *(const float4*)(x + (size_t)t * DIM + half * 32 + q * 4);
    float x2v = 0.f;
#pragma unroll
    for (int q = 0; q < 8; ++q) {
        x2v = fmaf(xh[q].x, xh[q].x, x2v);
        x2v = fmaf(xh[q].y, xh[q].y, x2v);
        x2v = fmaf(xh[q].z, xh[q].z, x2v);
        x2v = fmaf(xh[q].w, xh[q].w, x2v);
    }
    x2v += __shfl_xor(x2v, 1);   // full ||x||^2 in both pair lanes

    float bv = BIG;
    int   bi = 0x7fffffff;
    for (int e = 0; e < nq; ++e) {
        int blk = queue[e];
        int n = blk * 128 + w * 32 + (lane >> 1);   // whole WG per candidate
        if (n < NCODES) {   // pair-uniform predicate
            const float4* cp = (const float4*)(codes + (size_t)n * DIM + half * 32);
            float d = 0.f, cq = 0.f;
#pragma unroll
            for (int q = 0; q < 8; ++q) {
                float4 c4 = cp[q];
                d  = fmaf(xh[q].x, c4.x, d);
                d  = fmaf(xh[q].y, c4.y, d);
                d  = fmaf(xh[q].z, c4.z, d);
                d  = fmaf(xh[q].w, c4.w, d);
                cq = fmaf(c4.x, c4.x, cq);
                cq = fmaf(c4.y, c4.y, cq);
                cq = fmaf(c4.z, c4.z, cq);
                cq = fmaf(c4.w, c4.w, cq);
            }
            d  += __shfl_xor(d, 1);    // full 64-dim dot in both pair lanes
            cq += __shfl_xor(cq, 1);   // full ||c||^2 in both pair lanes
            float d2 = fmaxf(fmaf(-2.f, d, x2v + cq), 0.f);
            if (d2 < bv || (d2 == bv && n < bi)) { bv = d2; bi = n; }
        }
    }
#pragma unroll
    for (int m = 1; m < 64; m <<= 1) {
        float vv = __shfl_xor(bv, m);
        int   ii = __shfl_xor(bi, m);
        if (vv < bv || (vv == bv && ii < bi)) { bv = vv; bi = ii; }
    }
    if (lane == 0) { redf[4 + w] = bv; redi[w] = bi; }
    __syncthreads();
    if (tid == 0) {
        float fb = BIG;
        int   fi = 0x7fffffff;
#pragma unroll
        for (int i = 0; i < 4; ++i) {
            float vv = redf[4 + i];
            int   ii = redi[i];
            if (vv < fb || (vv == fb && ii < fi)) { fb = vv; fi = ii; }
        }
        out[t] = (fb <= THRESH) ? fi : -1;
    }
}

// ---------------------------------------------------------------------------
// Workspace: c2[50048]f | ch[50000*64]u16 | xh[2048*64]u16 |
//            bmT[2048*416]f  (~10.5 MB total; all offsets 16 B-aligned)
// ---------------------------------------------------------------------------
extern "C" void kernel_launch(void* const* d_in, const int* in_sizes, int n_in,
                              void* d_out, int out_size, void* d_ws, size_t ws_size,
                              hipStream_t stream) {
    const float* x     = (const float*)d_in[0];  // [2,1024,64]
    const float* codes = (const float*)d_in[1];  // [50000,64]

    float* c2 = (float*)d_ws;
    unsigned short* ch = (unsigned short*)(c2 + 50048);
    unsigned short* xh = ch + (size_t)NCODES * DIM;
    float* bmT = (float*)(xh + (size_t)NTOK * DIM);
    int* out = (int*)d_out;

    nn_prep_kernel<<<814, 256, 0, stream>>>(x, codes, ch, xh, c2);
    nn_stageA_kernel<<<1024, 256, 0, stream>>>(xh, ch, c2, bmT);
    nn_finalize_kernel<<<NTOK, 256, 0, stream>>>(x, codes, bmT, out);
}